// Round 9
// baseline (814.573 us; speedup 1.0000x reference)
//
#include <hip/hip_runtime.h>

// Flux2 double-stream attention block, bf16 MFMA pipeline, f32 final output.
// Stages: cvt(f32->bf16) -> QKV GEMM (8-phase 256^2) -> RMSnorm+RoPE(+V^T)
//         -> flash attn (32x32 MFMA, in-reg P, KVBLK=32, dbuf) -> out GEMM.
// ws layout (bytes):
//   [0,           22020096)  A_in bf16 [3584][3072]   } later aliased by V^T [24][128][3584]
//   [22020096,   135266304)  Wq bf16: img [9216][3072] then enc } later aliased by attn_out
//   [135266304,  173015040)  Wo bf16: img [3072][3072] then enc
//   [173015040,  239075328)  qkv bf16 [3584][9216]
// peak ws = 239,075,328 B.

typedef unsigned short u16;
typedef __attribute__((ext_vector_type(2))) unsigned short u16x2;
typedef __attribute__((ext_vector_type(4))) unsigned short u16x4;
typedef __attribute__((ext_vector_type(8))) unsigned short u16x8;
typedef __attribute__((ext_vector_type(8))) short bf16x8;
typedef __attribute__((ext_vector_type(4))) float f32x4;
typedef __attribute__((ext_vector_type(16))) float f32x16;
typedef __attribute__((ext_vector_type(4))) unsigned u32x4;

#define DEV __device__ __forceinline__

DEV u16 f2bf(float f) {
  unsigned u = __builtin_bit_cast(unsigned, f);
  u = (u + 0x7FFFu + ((u >> 16) & 1u)) >> 16;   // RNE
  return (u16)u;
}
DEV float bf2f(u16 s) { return __builtin_bit_cast(float, (unsigned)s << 16); }

DEV void store_out(u16* p, float v)  { *p = f2bf(v); }
DEV void store_out(float* p, float v) { *p = v; }

#define AS1(p) (const __attribute__((address_space(1))) void*)(p)
#define AS3(p) (__attribute__((address_space(3))) void*)(p)
#define GLL16(g, l) __builtin_amdgcn_global_load_lds(AS1(g), AS3(l), 16, 0, 0)

// raw barrier (NOT __syncthreads: that emits s_waitcnt vmcnt(0) and drains the
// counted-vmcnt pipeline). Compiler-only memory fences pin op order around it.
#define BAR() do { asm volatile("" ::: "memory"); __builtin_amdgcn_s_barrier(); \
                   asm volatile("" ::: "memory"); } while (0)
#define VMC8() asm volatile("s_waitcnt vmcnt(8)" ::: "memory")
#define VMC4() asm volatile("s_waitcnt vmcnt(4)" ::: "memory")
#define VMC0() asm volatile("s_waitcnt vmcnt(0)" ::: "memory")

// ---------------- fp32 -> bf16 convert ----------------
__global__ __launch_bounds__(256) void cvt_kernel(const float* __restrict__ src,
                                                  u16* __restrict__ dst, int n4) {
  int i = blockIdx.x * blockDim.x + threadIdx.x;
  int stride = gridDim.x * blockDim.x;
  for (; i < n4; i += stride) {
    float4 v = reinterpret_cast<const float4*>(src)[i];
    u16x4 o;
    o.x = f2bf(v.x); o.y = f2bf(v.y); o.z = f2bf(v.z); o.w = f2bf(v.w);
    reinterpret_cast<u16x4*>(dst)[i] = o;
  }
}

// ---------------- GEMM (8-phase 256x256): C = A[M][K] * B[N][K]^T (+bias) ----
// (unchanged — verified 8-phase counted-vmcnt structure)
template <typename OT>
__global__ __launch_bounds__(512, 2) void gemm256(
    const u16* __restrict__ A,
    const u16* __restrict__ Bimg, const u16* __restrict__ Benc,
    const float* __restrict__ biasImg, const float* __restrict__ biasEnc,
    OT* __restrict__ Cimg, OT* __restrict__ Cenc,
    int N, int K, int split, int nwg) {
  const int bid = blockIdx.x;
  const int swz = (bid & 7) * (nwg >> 3) + (bid >> 3);
  const int ntn = N >> 8;
  const int mt = swz / ntn, nt = swz % ntn;
  const int m0 = mt << 8, n0 = nt << 8;
  const u16* B = (m0 < split) ? Benc : Bimg;
  const float* bias = (m0 < split) ? biasEnc : biasImg;

  __shared__ u16 lds[2][2][16384];  // [buf][A=0/B=1][256 rows x 64 bf16] x2 = 128 KiB

  const int tid = threadIdx.x, w = tid >> 6, lane = tid & 63;
  const int wm = w >> 2, wn = w & 3;
  const int q = lane & 15, hi = lane >> 4;
  const size_t ldb = (size_t)K * 2;

  f32x4 acc[8][4];
#pragma unroll
  for (int i = 0; i < 8; ++i)
#pragma unroll
    for (int j = 0; j < 4; ++j)
#pragma unroll
      for (int r = 0; r < 4; ++r) acc[i][j][r] = 0.f;

  auto STAGE = [&](int d, int kt) {
    const char* sA = (const char*)A + (size_t)m0 * ldb + kt * 128;
    const char* sB = (const char*)B + (size_t)n0 * ldb + kt * 128;
    char* dA = (char*)&lds[d][0][0];
    char* dB = (char*)&lds[d][1][0];
#pragma unroll
    for (int j = 0; j < 4; ++j) {
      int base = j * 8192 + w * 1024;
      int off = base + lane * 16;
      int row = off >> 7;
      int src = (off & 127) ^ ((row & 7) << 4);
      GLL16(sA + (size_t)row * ldb + src, dA + base);
      GLL16(sB + (size_t)row * ldb + src, dB + base);
    }
  };
  auto LDA = [&](int d, int i, int ks) -> bf16x8 {
    int row = wm * 128 + i * 16 + q;
    int cb = ks * 64 + hi * 16;
    return *(const bf16x8*)((const char*)&lds[d][0][0] + row * 128 + (cb ^ ((row & 7) << 4)));
  };
  auto LDB = [&](int d, int j, int ks) -> bf16x8 {
    int row = wn * 64 + j * 16 + q;
    int cb = ks * 64 + hi * 16;
    return *(const bf16x8*)((const char*)&lds[d][1][0] + row * 128 + (cb ^ ((row & 7) << 4)));
  };

  auto HALF = [&](int d) {
    bf16x8 bfr[4][2];
#pragma unroll
    for (int ph = 0; ph < 4; ++ph) {
      if (ph == 0) {
#pragma unroll
        for (int j = 0; j < 4; ++j)
#pragma unroll
          for (int ks = 0; ks < 2; ++ks) bfr[j][ks] = LDB(d, j, ks);
      }
      bf16x8 af[2][2];
#pragma unroll
      for (int m = 0; m < 2; ++m)
#pragma unroll
        for (int ks = 0; ks < 2; ++ks) af[m][ks] = LDA(d, 2 * ph + m, ks);
      __builtin_amdgcn_s_setprio(1);
#pragma unroll
      for (int m = 0; m < 2; ++m)
#pragma unroll
        for (int j = 0; j < 4; ++j)
#pragma unroll
          for (int ks = 0; ks < 2; ++ks)
            acc[2 * ph + m][j] = __builtin_amdgcn_mfma_f32_16x16x32_bf16(
                af[m][ks], bfr[j][ks], acc[2 * ph + m][j], 0, 0, 0);
      __builtin_amdgcn_s_setprio(0);
      if (ph < 3) BAR();
    }
  };

  const int NT2 = K >> 7;
  STAGE(0, 0);
  STAGE(1, 1);
  VMC8();
  BAR();
  for (int t = 0; t < NT2; ++t) {
    HALF(0);
    BAR();
    if (t + 1 < NT2) { STAGE(0, 2 * t + 2); VMC8(); }
    else             VMC0();
    BAR();
    HALF(1);
    BAR();
    if (t + 1 < NT2) { STAGE(1, 2 * t + 3); VMC8(); }
    else             VMC0();
    BAR();
  }

#pragma unroll
  for (int i = 0; i < 8; ++i) {
    int rbase = m0 + wm * 128 + i * 16 + (hi << 2);
#pragma unroll
    for (int j = 0; j < 4; ++j) {
      int col = n0 + wn * 64 + j * 16 + q;
      float bv = bias ? bias[col] : 0.f;
#pragma unroll
      for (int r = 0; r < 4; ++r) {
        int row = rbase + r;
        float v = acc[i][j][r] + bv;
        if (row < split) store_out(&Cenc[(size_t)row * N + col], v);
        else             store_out(&Cimg[(size_t)(row - split) * N + col], v);
      }
    }
  }
}

// ---------------- per-head RMSnorm(q,k) + RoPE(q,k), emit V^T -----------------
// Q pre-scaled by log2(e)/sqrt(128) so attn scores land in log2 units.
__global__ __launch_bounds__(256) void norm_rope(
    u16* __restrict__ qkv, u16* __restrict__ vt,
    const float* __restrict__ cosT, const float* __restrict__ sinT,
    const float* __restrict__ nqw_img, const float* __restrict__ nkw_img,
    const float* __restrict__ nqw_enc, const float* __restrict__ nkw_enc) {
  const int h = blockIdx.y;
  const int s0 = blockIdx.x * 64;
  const int tid = threadIdx.x, w = tid >> 6, lane = tid & 63;
  const bool enc = (s0 < 512);
  const float* nqw = enc ? nqw_enc : nqw_img;
  const float* nkw = enc ? nkw_enc : nkw_img;
  const float SCL = 0.12751743f;  // log2(e)/sqrt(128)
  const float wq0 = nqw[2 * lane], wq1 = nqw[2 * lane + 1];
  const float wk0 = nkw[2 * lane], wk1 = nkw[2 * lane + 1];
  u16x8 va0, va1, vb0, vb1;
#pragma unroll
  for (int r = 0; r < 16; ++r) {
    const int s = s0 + w * 16 + r;
    const size_t rowb = (size_t)s * 9216 + h * 128 + 2 * lane;
    float2 cv = *(const float2*)&cosT[(size_t)s * 128 + 2 * lane];
    float2 sv = *(const float2*)&sinT[(size_t)s * 128 + 2 * lane];
    {  // Q
      u16x2 qu = *(u16x2*)&qkv[rowb];
      float x0 = bf2f(qu.x), x1 = bf2f(qu.y);
      float ss = x0 * x0 + x1 * x1;
#pragma unroll
      for (int d = 1; d < 64; d <<= 1) ss += __shfl_xor(ss, d);
      float rms = rsqrtf(ss * (1.0f / 128.0f) + 1e-5f);
      x0 *= rms * wq0; x1 *= rms * wq1;
      float o0 = (x0 * cv.x - x1 * sv.x) * SCL;
      float o1 = (x1 * cv.y + x0 * sv.y) * SCL;
      u16x2 ou; ou.x = f2bf(o0); ou.y = f2bf(o1);
      *(u16x2*)&qkv[rowb] = ou;
    }
    {  // K
      u16x2 ku = *(u16x2*)&qkv[rowb + 3072];
      float x0 = bf2f(ku.x), x1 = bf2f(ku.y);
      float ss = x0 * x0 + x1 * x1;
#pragma unroll
      for (int d = 1; d < 64; d <<= 1) ss += __shfl_xor(ss, d);
      float rms = rsqrtf(ss * (1.0f / 128.0f) + 1e-5f);
      x0 *= rms * wk0; x1 *= rms * wk1;
      float o0 = x0 * cv.x - x1 * sv.x;
      float o1 = x1 * cv.y + x0 * sv.y;
      u16x2 ou; ou.x = f2bf(o0); ou.y = f2bf(o1);
      *(u16x2*)&qkv[rowb + 3072] = ou;
    }
    {  // V -> registers for transposed store
      u16x2 vu = *(u16x2*)&qkv[rowb + 6144];
      if (r < 8) { va0[r] = vu.x; vb0[r] = vu.y; }
      else       { va1[r - 8] = vu.x; vb1[r - 8] = vu.y; }
    }
  }
  const size_t vbase = (size_t)h * 128 * 3584 + (size_t)(2 * lane) * 3584 + s0 + w * 16;
  *(u16x8*)&vt[vbase]            = va0;
  *(u16x8*)&vt[vbase + 8]        = va1;
  *(u16x8*)&vt[vbase + 3584]     = vb0;
  *(u16x8*)&vt[vbase + 3584 + 8] = vb1;
}

// ---------------- flash attention (32x32 MFMA, in-reg P, KVBLK=32) ----------
// grid 672 = 28 q-tiles x 24 heads (head-clustered per XCD). 4 waves x 32 q.
// KVBLK=32: LDS 32 KB -> ~5 blocks/CU resident; ALL 672 blocks co-resident
// (2.6/CU avg) -> no scheduler tail, deep wave overlap of the serial chain.
// Swapped QK^T 32x32x16 (lane q = lane&31; reg r -> k=(r&3)+8*(r>>2)+4*hi5).
// P packed to PV A-frags in-register (8 cvt_pk + 4 permlane32_swap, T12).
// K/V double-buffered, staged 2 tiles ahead, vmcnt(4) counted, 2 raw
// barriers/tile. Block-contiguous LDS: K[ds][lane], V[dt*2+ks][lane] 16B
// units -> every ds_read_b128 = 64 consecutive slots (0 bank conflicts, R8).
__global__ __launch_bounds__(256, 4) void attn_kernel(
    const u16* __restrict__ qkv, const u16* __restrict__ vt,
    u16* __restrict__ aout) {
  const int bid = blockIdx.x;
  const int qt = bid / 24;
  const int rr = bid % 24;
  const int h = (rr % 8) * 3 + (rr / 8);   // bijective; clusters heads per XCD
  const int tid = threadIdx.x, w = tid >> 6, lane = tid & 63;
  const int q32 = lane & 31, hi5 = lane >> 5;
  const int qbase = qt * 128 + w * 32;
  __shared__ u16 Klds[2][4096];   // 8 KB/buf: byte = ds*1024 + lane*16
  __shared__ u16 Vlds[2][4096];   // 8 KB/buf: byte = (dt*2+ks)*1024 + lane*16

  // Q as B-operand frags: n=q=lane&31, k(d) = ds*16 + hi5*8 + j
  bf16x8 aq[8];
  {
    const u16* qp = qkv + (size_t)(qbase + q32) * 9216 + h * 128 + hi5 * 8;
#pragma unroll
    for (int ds = 0; ds < 8; ++ds) aq[ds] = *(const bf16x8*)(qp + ds * 16);
  }
  float m_i = -1e30f, l_i = 0.f;  // stats for q-row (qbase + q32), log2 domain
  f32x16 o[4];                    // O: col d = dt*32 + q32, rows q(r)
#pragma unroll
  for (int dt = 0; dt < 4; ++dt)
#pragma unroll
    for (int r = 0; r < 16; ++r) o[dt][r] = 0.f;
  const size_t vhead = (size_t)h * 128 * 3584;

  // K stage: 8 units of 1KB (ds = w*2+j). src row = kt0 + q32 (k-row),
  // col byte = ds*32 + hi5*16 -> LDS K[ds][lane] = K[k=q32][d=ds*16+hi5*8+j].
  auto STAGE_K = [&](int kt0, int b) {
    const char* src = (const char*)(qkv + (size_t)(kt0 + q32) * 9216 + 3072 + h * 128) + hi5 * 16;
    char* dst = (char*)Klds[b] + w * 2048 + lane * 16;
#pragma unroll
    for (int j = 0; j < 2; ++j)
      GLL16(src + (w * 2 + j) * 32, dst + j * 1024);
  };
  // V stage: 8 units (u = w*2+j; dt = u>>1, ks = u&1). src d-row = dt*32+q32,
  // k byte = ks*32 + hi5*16 -> LDS V[u][lane] = V^T[d][k=kt0+ks*16+hi5*8+j].
  auto STAGE_V = [&](int kt0, int b) {
    char* dst = (char*)Vlds[b] + w * 2048 + lane * 16;
#pragma unroll
    for (int j = 0; j < 2; ++j) {
      const int u = w * 2 + j, dt = u >> 1, ks = u & 1;
      GLL16((const char*)(vt + vhead + (size_t)(dt * 32 + q32) * 3584 + kt0) + ks * 32 + hi5 * 16,
            dst + j * 1024);
    }
  };

  // pack 16 p-values (one 32x32 S-tile) into two PV A-frags (klocal 0-15,16-31)
  auto PACK = [&](const float* p, bf16x8* out2) {
    unsigned w0[4], w1[4];
#pragma unroll
    for (int g = 0; g < 4; ++g) {
      asm("v_cvt_pk_bf16_f32 %0, %1, %2" : "=v"(w0[g]) : "v"(p[4 * g + 0]), "v"(p[4 * g + 1]));
      asm("v_cvt_pk_bf16_f32 %0, %1, %2" : "=v"(w1[g]) : "v"(p[4 * g + 2]), "v"(p[4 * g + 3]));
    }
    asm("v_permlane32_swap_b32 %0, %1" : "+v"(w0[0]), "+v"(w0[1]));
    asm("v_permlane32_swap_b32 %0, %1" : "+v"(w1[0]), "+v"(w1[1]));
    asm("v_permlane32_swap_b32 %0, %1" : "+v"(w0[2]), "+v"(w0[3]));
    asm("v_permlane32_swap_b32 %0, %1" : "+v"(w1[2]), "+v"(w1[3]));
    u32x4 lo = {w0[0], w1[0], w0[1], w1[1]};   // klocal 0-15
    u32x4 hi_ = {w0[2], w1[2], w0[3], w1[3]};  // klocal 16-31
    out2[0] = __builtin_bit_cast(bf16x8, lo);
    out2[1] = __builtin_bit_cast(bf16x8, hi_);
  };

  const int NT = 112;  // 3584 / 32
  STAGE_K(0, 0);   STAGE_V(0, 0);
  STAGE_K(32, 1);  STAGE_V(32, 1);
  for (int t = 0; t < NT; ++t) {
    const int b = t & 1;
    if (t + 1 < NT) VMC4(); else VMC0();   // set t landed (t+1 still in flight)
    BAR();

    // ---- QK: S^T[32k][32q] over 8 d-steps ----
    f32x16 s0;
#pragma unroll
    for (int r = 0; r < 16; ++r) s0[r] = 0.f;
    __builtin_amdgcn_s_setprio(1);
#pragma unroll
    for (int ds = 0; ds < 8; ++ds) {
      bf16x8 k0 = *(const bf16x8*)((const char*)Klds[b] + ds * 1024 + lane * 16);
      s0 = __builtin_amdgcn_mfma_f32_32x32x16_bf16(k0, aq[ds], s0, 0, 0, 0);
    }
    __builtin_amdgcn_s_setprio(0);

    // ---- softmax (defer-max, log2 domain) ----
    float mx = s0[0];
#pragma unroll
    for (int r = 1; r < 16; ++r) mx = fmaxf(mx, s0[r]);
    mx = fmaxf(mx, __shfl_xor(mx, 32));
    if (!__all(mx - m_i <= 8.f)) {
      float mnew = fmaxf(m_i, mx);
      float alpha = __builtin_amdgcn_exp2f(m_i - mnew);
      m_i = mnew;
      l_i *= alpha;
#pragma unroll
      for (int r = 0; r < 16; ++r) {
        int qr = (r & 3) + 8 * (r >> 2) + 4 * hi5;
        float ar = __shfl(alpha, qr);
#pragma unroll
        for (int dt = 0; dt < 4; ++dt) o[dt][r] *= ar;
      }
    }
    float p0[16];
    float psum = 0.f;
#pragma unroll
    for (int r = 0; r < 16; ++r) { p0[r] = __builtin_amdgcn_exp2f(s0[r] - m_i); psum += p0[r]; }
    psum += __shfl_xor(psum, 32);
    l_i += psum;

    // ---- P -> A-frags in-register (no LDS) ----
    bf16x8 pa[2];
    PACK(p0, pa);

    // ---- PV: O += P V ----
    __builtin_amdgcn_s_setprio(1);
#pragma unroll
    for (int dt = 0; dt < 4; ++dt) {
#pragma unroll
      for (int ks = 0; ks < 2; ++ks) {
        bf16x8 bv = *(const bf16x8*)((const char*)Vlds[b] + (dt * 2 + ks) * 1024 + lane * 16);
        o[dt] = __builtin_amdgcn_mfma_f32_32x32x16_bf16(pa[ks], bv, o[dt], 0, 0, 0);
      }
    }
    __builtin_amdgcn_s_setprio(0);
    BAR();                         // all waves done reading buf b
    if (t + 2 < NT) { STAGE_K((t + 2) * 32, b); STAGE_V((t + 2) * 32, b); }
  }

  // epilogue: O /= l (per-row l via shfl), bf16 scatter to attn_out[s][h*128+d]
#pragma unroll
  for (int r = 0; r < 16; ++r) {
    const int qr = (r & 3) + 8 * (r >> 2) + 4 * hi5;
    const float lr = __shfl(l_i, qr);
    const float inv = 1.0f / lr;
    const size_t srow = (size_t)(qbase + qr) * 3072 + h * 128 + q32;
#pragma unroll
    for (int dt = 0; dt < 4; ++dt)
      aout[srow + dt * 32] = f2bf(o[dt][r] * inv);
  }
}

extern "C" void kernel_launch(void* const* d_in, const int* in_sizes, int n_in,
                              void* d_out, int out_size, void* d_ws, size_t ws_size,
                              hipStream_t stream) {
  (void)in_sizes; (void)n_in; (void)out_size; (void)ws_size;
  const float* hs    = (const float*)d_in[0];
  const float* ehs   = (const float*)d_in[1];
  const float* cosT  = (const float*)d_in[2];
  const float* sinT  = (const float*)d_in[3];
  const float* Wqkv  = (const float*)d_in[4];
  const float* Wadd  = (const float*)d_in[5];
  const float* bAdd  = (const float*)d_in[6];
  const float* nqw   = (const float*)d_in[7];
  const float* nkw   = (const float*)d_in[8];
  const float* naqw  = (const float*)d_in[9];
  const float* nakw  = (const float*)d_in[10];
  const float* Wout  = (const float*)d_in[11];
  const float* bout  = (const float*)d_in[12];
  const float* Waddo = (const float*)d_in[13];
  const float* baddo = (const float*)d_in[14];

  char* ws = (char*)d_ws;
  u16* Ain = (u16*)(ws);                       // [3584][3072]
  u16* WqI = (u16*)(ws + 22020096);            // [9216][3072]
  u16* WqE = WqI + (size_t)9216 * 3072;
  u16* WoI = (u16*)(ws + 135266304);           // [3072][3072]
  u16* WoE = WoI + (size_t)3072 * 3072;
  u16* qkv = (u16*)(ws + 173015040);           // [3584][9216]
  u16* vt   = Ain;  // alias: A_in dead after QKV GEMM
  u16* aout = WqI;  // alias: W_qkv dead after QKV GEMM

  cvt_kernel<<<1024, 256, 0, stream>>>(ehs,   Ain,                      512 * 3072 / 4);
  cvt_kernel<<<1024, 256, 0, stream>>>(hs,    Ain + (size_t)512 * 3072, 3072 * 3072 / 4);
  cvt_kernel<<<2048, 256, 0, stream>>>(Wqkv,  WqI, 9216 * 3072 / 4);
  cvt_kernel<<<2048, 256, 0, stream>>>(Wadd,  WqE, 9216 * 3072 / 4);
  cvt_kernel<<<1024, 256, 0, stream>>>(Wout,  WoI, 3072 * 3072 / 4);
  cvt_kernel<<<1024, 256, 0, stream>>>(Waddo, WoE, 3072 * 3072 / 4);

  // QKV: [3584][9216] = A_in x W^T (+ bias on enc rows), bf16 out (internal)
  gemm256<u16><<<dim3(504), 512, 0, stream>>>(Ain, WqI, WqE, nullptr, bAdd,
                                              qkv + (size_t)512 * 9216, qkv, 9216, 3072, 512, 504);
  norm_rope<<<dim3(56, 24), 256, 0, stream>>>(qkv, vt, cosT, sinT, nqw, nkw, naqw, nakw);
  attn_kernel<<<dim3(672), 256, 0, stream>>>(qkv, vt, aout);
  // out proj: FLOAT32 output — img rows -> d_out[0:3072*3072], enc rows after
  float* outp = (float*)d_out;
  gemm256<float><<<dim3(168), 512, 0, stream>>>(aout, WoI, WoE, bout, baddo,
                                                outp, outp + (size_t)3072 * 3072, 3072, 3072, 512, 168);
}

// Round 10
// 642.022 us; speedup vs baseline: 1.2688x; 1.2688x over previous
//
#include <hip/hip_runtime.h>

// Flux2 double-stream attention block, bf16 MFMA pipeline, f32 final output.
// Stages: cvt(f32->bf16) -> QKV GEMM (8-phase 256^2) -> RMSnorm+RoPE(+V^T)
//         -> flash attn (32x32 MFMA, in-reg P, KVBLK=32, dbuf) -> out GEMM.
// ws layout (bytes):
//   [0,           22020096)  A_in bf16 [3584][3072]   } later aliased by V^T [24][128][3584]
//   [22020096,   135266304)  Wq bf16: img [9216][3072] then enc } later aliased by attn_out
//   [135266304,  173015040)  Wo bf16: img [3072][3072] then enc
//   [173015040,  239075328)  qkv bf16 [3584][9216]
// peak ws = 239,075,328 B.

typedef unsigned short u16;
typedef __attribute__((ext_vector_type(2))) unsigned short u16x2;
typedef __attribute__((ext_vector_type(4))) unsigned short u16x4;
typedef __attribute__((ext_vector_type(8))) unsigned short u16x8;
typedef __attribute__((ext_vector_type(8))) short bf16x8;
typedef __attribute__((ext_vector_type(4))) float f32x4;
typedef __attribute__((ext_vector_type(16))) float f32x16;
typedef __attribute__((ext_vector_type(4))) unsigned u32x4;

#define DEV __device__ __forceinline__

DEV u16 f2bf(float f) {
  unsigned u = __builtin_bit_cast(unsigned, f);
  u = (u + 0x7FFFu + ((u >> 16) & 1u)) >> 16;   // RNE
  return (u16)u;
}
DEV float bf2f(u16 s) { return __builtin_bit_cast(float, (unsigned)s << 16); }

DEV void store_out(u16* p, float v)  { *p = f2bf(v); }
DEV void store_out(float* p, float v) { *p = v; }

#define AS1(p) (const __attribute__((address_space(1))) void*)(p)
#define AS3(p) (__attribute__((address_space(3))) void*)(p)
#define GLL16(g, l) __builtin_amdgcn_global_load_lds(AS1(g), AS3(l), 16, 0, 0)

// raw barrier (NOT __syncthreads: that emits s_waitcnt vmcnt(0) and drains the
// counted-vmcnt pipeline). Compiler-only memory fences pin op order around it.
#define BAR() do { asm volatile("" ::: "memory"); __builtin_amdgcn_s_barrier(); \
                   asm volatile("" ::: "memory"); } while (0)
#define VMC8() asm volatile("s_waitcnt vmcnt(8)" ::: "memory")
#define VMC4() asm volatile("s_waitcnt vmcnt(4)" ::: "memory")
#define VMC0() asm volatile("s_waitcnt vmcnt(0)" ::: "memory")

// ---------------- fp32 -> bf16 convert ----------------
__global__ __launch_bounds__(256) void cvt_kernel(const float* __restrict__ src,
                                                  u16* __restrict__ dst, int n4) {
  int i = blockIdx.x * blockDim.x + threadIdx.x;
  int stride = gridDim.x * blockDim.x;
  for (; i < n4; i += stride) {
    float4 v = reinterpret_cast<const float4*>(src)[i];
    u16x4 o;
    o.x = f2bf(v.x); o.y = f2bf(v.y); o.z = f2bf(v.z); o.w = f2bf(v.w);
    reinterpret_cast<u16x4*>(dst)[i] = o;
  }
}

// ---------------- GEMM (8-phase 256x256): C = A[M][K] * B[N][K]^T (+bias) ----
// (unchanged — verified 8-phase counted-vmcnt structure)
template <typename OT>
__global__ __launch_bounds__(512, 2) void gemm256(
    const u16* __restrict__ A,
    const u16* __restrict__ Bimg, const u16* __restrict__ Benc,
    const float* __restrict__ biasImg, const float* __restrict__ biasEnc,
    OT* __restrict__ Cimg, OT* __restrict__ Cenc,
    int N, int K, int split, int nwg) {
  const int bid = blockIdx.x;
  const int swz = (bid & 7) * (nwg >> 3) + (bid >> 3);
  const int ntn = N >> 8;
  const int mt = swz / ntn, nt = swz % ntn;
  const int m0 = mt << 8, n0 = nt << 8;
  const u16* B = (m0 < split) ? Benc : Bimg;
  const float* bias = (m0 < split) ? biasEnc : biasImg;

  __shared__ u16 lds[2][2][16384];  // [buf][A=0/B=1][256 rows x 64 bf16] x2 = 128 KiB

  const int tid = threadIdx.x, w = tid >> 6, lane = tid & 63;
  const int wm = w >> 2, wn = w & 3;
  const int q = lane & 15, hi = lane >> 4;
  const size_t ldb = (size_t)K * 2;

  f32x4 acc[8][4];
#pragma unroll
  for (int i = 0; i < 8; ++i)
#pragma unroll
    for (int j = 0; j < 4; ++j)
#pragma unroll
      for (int r = 0; r < 4; ++r) acc[i][j][r] = 0.f;

  auto STAGE = [&](int d, int kt) {
    const char* sA = (const char*)A + (size_t)m0 * ldb + kt * 128;
    const char* sB = (const char*)B + (size_t)n0 * ldb + kt * 128;
    char* dA = (char*)&lds[d][0][0];
    char* dB = (char*)&lds[d][1][0];
#pragma unroll
    for (int j = 0; j < 4; ++j) {
      int base = j * 8192 + w * 1024;
      int off = base + lane * 16;
      int row = off >> 7;
      int src = (off & 127) ^ ((row & 7) << 4);
      GLL16(sA + (size_t)row * ldb + src, dA + base);
      GLL16(sB + (size_t)row * ldb + src, dB + base);
    }
  };
  auto LDA = [&](int d, int i, int ks) -> bf16x8 {
    int row = wm * 128 + i * 16 + q;
    int cb = ks * 64 + hi * 16;
    return *(const bf16x8*)((const char*)&lds[d][0][0] + row * 128 + (cb ^ ((row & 7) << 4)));
  };
  auto LDB = [&](int d, int j, int ks) -> bf16x8 {
    int row = wn * 64 + j * 16 + q;
    int cb = ks * 64 + hi * 16;
    return *(const bf16x8*)((const char*)&lds[d][1][0] + row * 128 + (cb ^ ((row & 7) << 4)));
  };

  auto HALF = [&](int d) {
    bf16x8 bfr[4][2];
#pragma unroll
    for (int ph = 0; ph < 4; ++ph) {
      if (ph == 0) {
#pragma unroll
        for (int j = 0; j < 4; ++j)
#pragma unroll
          for (int ks = 0; ks < 2; ++ks) bfr[j][ks] = LDB(d, j, ks);
      }
      bf16x8 af[2][2];
#pragma unroll
      for (int m = 0; m < 2; ++m)
#pragma unroll
        for (int ks = 0; ks < 2; ++ks) af[m][ks] = LDA(d, 2 * ph + m, ks);
      __builtin_amdgcn_s_setprio(1);
#pragma unroll
      for (int m = 0; m < 2; ++m)
#pragma unroll
        for (int j = 0; j < 4; ++j)
#pragma unroll
          for (int ks = 0; ks < 2; ++ks)
            acc[2 * ph + m][j] = __builtin_amdgcn_mfma_f32_16x16x32_bf16(
                af[m][ks], bfr[j][ks], acc[2 * ph + m][j], 0, 0, 0);
      __builtin_amdgcn_s_setprio(0);
      if (ph < 3) BAR();
    }
  };

  const int NT2 = K >> 7;
  STAGE(0, 0);
  STAGE(1, 1);
  VMC8();
  BAR();
  for (int t = 0; t < NT2; ++t) {
    HALF(0);
    BAR();
    if (t + 1 < NT2) { STAGE(0, 2 * t + 2); VMC8(); }
    else             VMC0();
    BAR();
    HALF(1);
    BAR();
    if (t + 1 < NT2) { STAGE(1, 2 * t + 3); VMC8(); }
    else             VMC0();
    BAR();
  }

#pragma unroll
  for (int i = 0; i < 8; ++i) {
    int rbase = m0 + wm * 128 + i * 16 + (hi << 2);
#pragma unroll
    for (int j = 0; j < 4; ++j) {
      int col = n0 + wn * 64 + j * 16 + q;
      float bv = bias ? bias[col] : 0.f;
#pragma unroll
      for (int r = 0; r < 4; ++r) {
        int row = rbase + r;
        float v = acc[i][j][r] + bv;
        if (row < split) store_out(&Cenc[(size_t)row * N + col], v);
        else             store_out(&Cimg[(size_t)(row - split) * N + col], v);
      }
    }
  }
}

// ---------------- per-head RMSnorm(q,k) + RoPE(q,k), emit V^T -----------------
// Q pre-scaled by log2(e)/sqrt(128) so attn scores land in log2 units.
__global__ __launch_bounds__(256) void norm_rope(
    u16* __restrict__ qkv, u16* __restrict__ vt,
    const float* __restrict__ cosT, const float* __restrict__ sinT,
    const float* __restrict__ nqw_img, const float* __restrict__ nkw_img,
    const float* __restrict__ nqw_enc, const float* __restrict__ nkw_enc) {
  const int h = blockIdx.y;
  const int s0 = blockIdx.x * 64;
  const int tid = threadIdx.x, w = tid >> 6, lane = tid & 63;
  const bool enc = (s0 < 512);
  const float* nqw = enc ? nqw_enc : nqw_img;
  const float* nkw = enc ? nkw_enc : nkw_img;
  const float SCL = 0.12751743f;  // log2(e)/sqrt(128)
  const float wq0 = nqw[2 * lane], wq1 = nqw[2 * lane + 1];
  const float wk0 = nkw[2 * lane], wk1 = nkw[2 * lane + 1];
  u16x8 va0, va1, vb0, vb1;
#pragma unroll
  for (int r = 0; r < 16; ++r) {
    const int s = s0 + w * 16 + r;
    const size_t rowb = (size_t)s * 9216 + h * 128 + 2 * lane;
    float2 cv = *(const float2*)&cosT[(size_t)s * 128 + 2 * lane];
    float2 sv = *(const float2*)&sinT[(size_t)s * 128 + 2 * lane];
    {  // Q
      u16x2 qu = *(u16x2*)&qkv[rowb];
      float x0 = bf2f(qu.x), x1 = bf2f(qu.y);
      float ss = x0 * x0 + x1 * x1;
#pragma unroll
      for (int d = 1; d < 64; d <<= 1) ss += __shfl_xor(ss, d);
      float rms = rsqrtf(ss * (1.0f / 128.0f) + 1e-5f);
      x0 *= rms * wq0; x1 *= rms * wq1;
      float o0 = (x0 * cv.x - x1 * sv.x) * SCL;
      float o1 = (x1 * cv.y + x0 * sv.y) * SCL;
      u16x2 ou; ou.x = f2bf(o0); ou.y = f2bf(o1);
      *(u16x2*)&qkv[rowb] = ou;
    }
    {  // K
      u16x2 ku = *(u16x2*)&qkv[rowb + 3072];
      float x0 = bf2f(ku.x), x1 = bf2f(ku.y);
      float ss = x0 * x0 + x1 * x1;
#pragma unroll
      for (int d = 1; d < 64; d <<= 1) ss += __shfl_xor(ss, d);
      float rms = rsqrtf(ss * (1.0f / 128.0f) + 1e-5f);
      x0 *= rms * wk0; x1 *= rms * wk1;
      float o0 = x0 * cv.x - x1 * sv.x;
      float o1 = x1 * cv.y + x0 * sv.y;
      u16x2 ou; ou.x = f2bf(o0); ou.y = f2bf(o1);
      *(u16x2*)&qkv[rowb + 3072] = ou;
    }
    {  // V -> registers for transposed store
      u16x2 vu = *(u16x2*)&qkv[rowb + 6144];
      if (r < 8) { va0[r] = vu.x; vb0[r] = vu.y; }
      else       { va1[r - 8] = vu.x; vb1[r - 8] = vu.y; }
    }
  }
  const size_t vbase = (size_t)h * 128 * 3584 + (size_t)(2 * lane) * 3584 + s0 + w * 16;
  *(u16x8*)&vt[vbase]            = va0;
  *(u16x8*)&vt[vbase + 8]        = va1;
  *(u16x8*)&vt[vbase + 3584]     = vb0;
  *(u16x8*)&vt[vbase + 3584 + 8] = vb1;
}

// ---------------- flash attention (32x32 MFMA, in-reg P, KVBLK=32) ----------
// grid 672 = 28 q-tiles x 24 heads (head-clustered per XCD). 4 waves x 32 q.
// KVBLK=32: LDS 32 KB. launch_bounds (256,2): R9's (256,4) capped arch-VGPR
// at 64 and spilled ~53 MB of scratch into the inner loop (WRITE_SIZE 75 MB,
// dur +38%). With natural allocation (~150 total incl. AGPR acc) we get
// 3 waves/SIMD by VGPR and 5 blocks/CU by LDS -> ~3 blocks/CU, no spill.
// Swapped QK^T 32x32x16 (lane q = lane&31; reg r -> k=(r&3)+8*(r>>2)+4*hi5).
// P packed to PV A-frags in-register (8 cvt_pk + 4 permlane32_swap, T12).
// K/V double-buffered, staged 2 tiles ahead, vmcnt(4) counted, 2 raw
// barriers/tile. Block-contiguous LDS: K[ds][lane], V[dt*2+ks][lane] 16B
// units -> every ds_read_b128 = 64 consecutive slots (0 bank conflicts, R8).
__global__ __launch_bounds__(256, 2) void attn_kernel(
    const u16* __restrict__ qkv, const u16* __restrict__ vt,
    u16* __restrict__ aout) {
  const int bid = blockIdx.x;
  const int qt = bid / 24;
  const int rr = bid % 24;
  const int h = (rr % 8) * 3 + (rr / 8);   // bijective; clusters heads per XCD
  const int tid = threadIdx.x, w = tid >> 6, lane = tid & 63;
  const int q32 = lane & 31, hi5 = lane >> 5;
  const int qbase = qt * 128 + w * 32;
  __shared__ u16 Klds[2][4096];   // 8 KB/buf: byte = ds*1024 + lane*16
  __shared__ u16 Vlds[2][4096];   // 8 KB/buf: byte = (dt*2+ks)*1024 + lane*16

  // Q as B-operand frags: n=q=lane&31, k(d) = ds*16 + hi5*8 + j
  bf16x8 aq[8];
  {
    const u16* qp = qkv + (size_t)(qbase + q32) * 9216 + h * 128 + hi5 * 8;
#pragma unroll
    for (int ds = 0; ds < 8; ++ds) aq[ds] = *(const bf16x8*)(qp + ds * 16);
  }
  float m_i = -1e30f, l_i = 0.f;  // stats for q-row (qbase + q32), log2 domain
  f32x16 o[4];                    // O: col d = dt*32 + q32, rows q(r)
#pragma unroll
  for (int dt = 0; dt < 4; ++dt)
#pragma unroll
    for (int r = 0; r < 16; ++r) o[dt][r] = 0.f;
  const size_t vhead = (size_t)h * 128 * 3584;

  // K stage: 8 units of 1KB (ds = w*2+j). src row = kt0 + q32 (k-row),
  // col byte = ds*32 + hi5*16 -> LDS K[ds][lane] = K[k=q32][d=ds*16+hi5*8+j].
  auto STAGE_K = [&](int kt0, int b) {
    const char* src = (const char*)(qkv + (size_t)(kt0 + q32) * 9216 + 3072 + h * 128) + hi5 * 16;
    char* dst = (char*)Klds[b] + w * 2048 + lane * 16;
#pragma unroll
    for (int j = 0; j < 2; ++j)
      GLL16(src + (w * 2 + j) * 32, dst + j * 1024);
  };
  // V stage: 8 units (u = w*2+j; dt = u>>1, ks = u&1). src d-row = dt*32+q32,
  // k byte = ks*32 + hi5*16 -> LDS V[u][lane] = V^T[d][k=kt0+ks*16+hi5*8+j].
  auto STAGE_V = [&](int kt0, int b) {
    char* dst = (char*)Vlds[b] + w * 2048 + lane * 16;
#pragma unroll
    for (int j = 0; j < 2; ++j) {
      const int u = w * 2 + j, dt = u >> 1, ks = u & 1;
      GLL16((const char*)(vt + vhead + (size_t)(dt * 32 + q32) * 3584 + kt0) + ks * 32 + hi5 * 16,
            dst + j * 1024);
    }
  };

  // pack 16 p-values (one 32x32 S-tile) into two PV A-frags (klocal 0-15,16-31)
  auto PACK = [&](const float* p, bf16x8* out2) {
    unsigned w0[4], w1[4];
#pragma unroll
    for (int g = 0; g < 4; ++g) {
      asm("v_cvt_pk_bf16_f32 %0, %1, %2" : "=v"(w0[g]) : "v"(p[4 * g + 0]), "v"(p[4 * g + 1]));
      asm("v_cvt_pk_bf16_f32 %0, %1, %2" : "=v"(w1[g]) : "v"(p[4 * g + 2]), "v"(p[4 * g + 3]));
    }
    asm("v_permlane32_swap_b32 %0, %1" : "+v"(w0[0]), "+v"(w0[1]));
    asm("v_permlane32_swap_b32 %0, %1" : "+v"(w1[0]), "+v"(w1[1]));
    asm("v_permlane32_swap_b32 %0, %1" : "+v"(w0[2]), "+v"(w0[3]));
    asm("v_permlane32_swap_b32 %0, %1" : "+v"(w1[2]), "+v"(w1[3]));
    u32x4 lo = {w0[0], w1[0], w0[1], w1[1]};   // klocal 0-15
    u32x4 hi_ = {w0[2], w1[2], w0[3], w1[3]};  // klocal 16-31
    out2[0] = __builtin_bit_cast(bf16x8, lo);
    out2[1] = __builtin_bit_cast(bf16x8, hi_);
  };

  const int NT = 112;  // 3584 / 32
  STAGE_K(0, 0);   STAGE_V(0, 0);
  STAGE_K(32, 1);  STAGE_V(32, 1);
  for (int t = 0; t < NT; ++t) {
    const int b = t & 1;
    if (t + 1 < NT) VMC4(); else VMC0();   // set t landed (t+1 still in flight)
    BAR();

    // ---- QK: S^T[32k][32q] over 8 d-steps ----
    f32x16 s0;
#pragma unroll
    for (int r = 0; r < 16; ++r) s0[r] = 0.f;
    __builtin_amdgcn_s_setprio(1);
#pragma unroll
    for (int ds = 0; ds < 8; ++ds) {
      bf16x8 k0 = *(const bf16x8*)((const char*)Klds[b] + ds * 1024 + lane * 16);
      s0 = __builtin_amdgcn_mfma_f32_32x32x16_bf16(k0, aq[ds], s0, 0, 0, 0);
    }
    __builtin_amdgcn_s_setprio(0);

    // ---- softmax (defer-max, log2 domain) ----
    float mx = s0[0];
#pragma unroll
    for (int r = 1; r < 16; ++r) mx = fmaxf(mx, s0[r]);
    mx = fmaxf(mx, __shfl_xor(mx, 32));
    if (!__all(mx - m_i <= 8.f)) {
      float mnew = fmaxf(m_i, mx);
      float alpha = __builtin_amdgcn_exp2f(m_i - mnew);
      m_i = mnew;
      l_i *= alpha;
#pragma unroll
      for (int r = 0; r < 16; ++r) {
        int qr = (r & 3) + 8 * (r >> 2) + 4 * hi5;
        float ar = __shfl(alpha, qr);
#pragma unroll
        for (int dt = 0; dt < 4; ++dt) o[dt][r] *= ar;
      }
    }
    float p0[16];
    float psum = 0.f;
#pragma unroll
    for (int r = 0; r < 16; ++r) { p0[r] = __builtin_amdgcn_exp2f(s0[r] - m_i); psum += p0[r]; }
    psum += __shfl_xor(psum, 32);
    l_i += psum;

    // ---- P -> A-frags in-register (no LDS) ----
    bf16x8 pa[2];
    PACK(p0, pa);

    // ---- PV: O += P V ----
    __builtin_amdgcn_s_setprio(1);
#pragma unroll
    for (int dt = 0; dt < 4; ++dt) {
#pragma unroll
      for (int ks = 0; ks < 2; ++ks) {
        bf16x8 bv = *(const bf16x8*)((const char*)Vlds[b] + (dt * 2 + ks) * 1024 + lane * 16);
        o[dt] = __builtin_amdgcn_mfma_f32_32x32x16_bf16(pa[ks], bv, o[dt], 0, 0, 0);
      }
    }
    __builtin_amdgcn_s_setprio(0);
    BAR();                         // all waves done reading buf b
    if (t + 2 < NT) { STAGE_K((t + 2) * 32, b); STAGE_V((t + 2) * 32, b); }
  }

  // epilogue: O /= l (per-row l via shfl), bf16 scatter to attn_out[s][h*128+d]
#pragma unroll
  for (int r = 0; r < 16; ++r) {
    const int qr = (r & 3) + 8 * (r >> 2) + 4 * hi5;
    const float lr = __shfl(l_i, qr);
    const float inv = 1.0f / lr;
    const size_t srow = (size_t)(qbase + qr) * 3072 + h * 128 + q32;
#pragma unroll
    for (int dt = 0; dt < 4; ++dt)
      aout[srow + dt * 32] = f2bf(o[dt][r] * inv);
  }
}

extern "C" void kernel_launch(void* const* d_in, const int* in_sizes, int n_in,
                              void* d_out, int out_size, void* d_ws, size_t ws_size,
                              hipStream_t stream) {
  (void)in_sizes; (void)n_in; (void)out_size; (void)ws_size;
  const float* hs    = (const float*)d_in[0];
  const float* ehs   = (const float*)d_in[1];
  const float* cosT  = (const float*)d_in[2];
  const float* sinT  = (const float*)d_in[3];
  const float* Wqkv  = (const float*)d_in[4];
  const float* Wadd  = (const float*)d_in[5];
  const float* bAdd  = (const float*)d_in[6];
  const float* nqw   = (const float*)d_in[7];
  const float* nkw   = (const float*)d_in[8];
  const float* naqw  = (const float*)d_in[9];
  const float* nakw  = (const float*)d_in[10];
  const float* Wout  = (const float*)d_in[11];
  const float* bout  = (const float*)d_in[12];
  const float* Waddo = (const float*)d_in[13];
  const float* baddo = (const float*)d_in[14];

  char* ws = (char*)d_ws;
  u16* Ain = (u16*)(ws);                       // [3584][3072]
  u16* WqI = (u16*)(ws + 22020096);            // [9216][3072]
  u16* WqE = WqI + (size_t)9216 * 3072;
  u16* WoI = (u16*)(ws + 135266304);           // [3072][3072]
  u16* WoE = WoI + (size_t)3072 * 3072;
  u16* qkv = (u16*)(ws + 173015040);           // [3584][9216]
  u16* vt   = Ain;  // alias: A_in dead after QKV GEMM
  u16* aout = WqI;  // alias: W_qkv dead after QKV GEMM

  cvt_kernel<<<1024, 256, 0, stream>>>(ehs,   Ain,                      512 * 3072 / 4);
  cvt_kernel<<<1024, 256, 0, stream>>>(hs,    Ain + (size_t)512 * 3072, 3072 * 3072 / 4);
  cvt_kernel<<<2048, 256, 0, stream>>>(Wqkv,  WqI, 9216 * 3072 / 4);
  cvt_kernel<<<2048, 256, 0, stream>>>(Wadd,  WqE, 9216 * 3072 / 4);
  cvt_kernel<<<1024, 256, 0, stream>>>(Wout,  WoI, 3072 * 3072 / 4);
  cvt_kernel<<<1024, 256, 0, stream>>>(Waddo, WoE, 3072 * 3072 / 4);

  // QKV: [3584][9216] = A_in x W^T (+ bias on enc rows), bf16 out (internal)
  gemm256<u16><<<dim3(504), 512, 0, stream>>>(Ain, WqI, WqE, nullptr, bAdd,
                                              qkv + (size_t)512 * 9216, qkv, 9216, 3072, 512, 504);
  norm_rope<<<dim3(56, 24), 256, 0, stream>>>(qkv, vt, cosT, sinT, nqw, nkw, naqw, nakw);
  attn_kernel<<<dim3(672), 256, 0, stream>>>(qkv, vt, aout);
  // out proj: FLOAT32 output — img rows -> d_out[0:3072*3072], enc rows after
  float* outp = (float*)d_out;
  gemm256<float><<<dim3(168), 512, 0, stream>>>(aout, WoI, WoE, bout, baddo,
                                                outp, outp + (size_t)3072 * 3072, 3072, 3072, 512, 168);
}